// Round 3
// baseline (4638.920 us; speedup 1.0000x reference)
//
#include <hip/hip_runtime.h>
#include <math.h>

// SLSTM: T=1024, B=256, C=14, H=128, 4H=512, NC=7. All fp32.
//
// Round 3: 2 gate-rows per thread (j and j+256), 256-thread blocks.
// One readlane broadcast feeds two FMAs (float2 accumulators; compiler may
// pack into v_pk_fma_f32). Per-output-row summation order is bit-identical
// to the round-2 passing kernel (k%4 accumulator partition, (a0+a1)+(a2+a3)).
//   R1: layer-1 recurrence, 1 block/batch, W rows j & j+256 in VGPRs.
//       Threads <128 own gates i,g of h=j; threads >=128 own f,o of h=j-128
//       and pass sigf(f),sigf(o) via LDS. Writes packed spike bits.
//   G2: Z2 = spk1 @ W_ih2^T + biases. 2 cols/thread, 2048 blocks.
//   R2: layer-2 recurrence, same structure, Z2 prefetched from global.
//   FC: out = (sum_t mem2 / T) @ fc_w^T + fc_b.

#define T_STEPS 1024
#define BATCH   256
#define H       128
#define G4      512
#define NC      7

__device__ __forceinline__ float sigf(float v) { return 1.0f / (1.0f + expf(-v)); }

__device__ __forceinline__ float bcast(float v, int lane) {
  return __int_as_float(__builtin_amdgcn_readlane(__float_as_int(v), lane));
}

// acc.x chain = row A (order identical to round-2 scalar chain), acc.y = row B
__device__ __forceinline__ void fma2(float2& a, const float2 w, const float m) {
  a.x = fmaf(w.x, m, a.x);
  a.y = fmaf(w.y, m, a.y);
}

// ---------------------------------------------------------------- layer 1
__global__ __launch_bounds__(256, 1) void r1_kernel(
    const float* __restrict__ x,      // [T,B,14]
    const float* __restrict__ Wih1,   // [512,14]
    const float* __restrict__ Whh1,   // [512,128]
    const float* __restrict__ bih1,
    const float* __restrict__ bhh1,
    const float* __restrict__ thr1p,
    unsigned long long* __restrict__ spk)  // [T,B,2] packed bits
{
  const int b    = blockIdx.x;
  const int j    = threadIdx.x;        // 0..255; owns gate rows j and j+256
  const int lane = j & 63;
  const int wav  = j >> 6;             // 0..3

  __shared__ __align__(16) float xbuf[T_STEPS * 16];  // x padded 14->16, 64 KB
  __shared__ float membuf[H];
  __shared__ float2 fgbuf[H];          // {sigf(f), sigf(o)} per h

  // weights: rows j (A) and j+256 (B), interleaved as float2
  float2 wih[14];
#pragma unroll
  for (int c = 0; c < 14; ++c) {
    wih[c].x = Wih1[j * 14 + c];
    wih[c].y = Wih1[(j + 256) * 14 + c];
  }
  float2 w2[128];
#pragma unroll
  for (int k = 0; k < 128; ++k) {
    w2[k].x = Whh1[j * 128 + k];
    w2[k].y = Whh1[(j + 256) * 128 + k];
  }
  const float biasA = bih1[j] + bhh1[j];
  const float biasB = bih1[j + 256] + bhh1[j + 256];
  const float thr   = thr1p[0];

  // stage this batch element's whole input sequence into LDS (one-time)
  for (int m = j; m < T_STEPS * 16; m += 256) {
    int t = m >> 4, c = m & 15;
    xbuf[m] = (c < 14) ? x[(t * BATCH + b) * 14 + c] : 0.f;
  }

  float syn = 0.f, mem = 0.f;          // state for h=j (threads <128 only)
  if (j < H) membuf[j] = 0.f;
  __syncthreads();
  float vLow = 0.f, vHigh = 0.f;       // membuf[lane], membuf[64+lane]

  for (int t = 0; t < T_STEPS; ++t) {
    float2 a0 = {0.f, 0.f}, a1 = {0.f, 0.f}, a2 = {0.f, 0.f}, a3 = {0.f, 0.f};
    // x part: c 0..3 -> a0, 4..7 -> a1, 8..11 -> a2, 12..13 -> a3 (round-2 order)
    const float4* xr = (const float4*)&xbuf[t << 4];
    float4 v;
    v = xr[0];
    a0.x += wih[0].x * v.x + wih[1].x * v.y + wih[2].x * v.z + wih[3].x * v.w;
    a0.y += wih[0].y * v.x + wih[1].y * v.y + wih[2].y * v.z + wih[3].y * v.w;
    v = xr[1];
    a1.x += wih[4].x * v.x + wih[5].x * v.y + wih[6].x * v.z + wih[7].x * v.w;
    a1.y += wih[4].y * v.x + wih[5].y * v.y + wih[6].y * v.z + wih[7].y * v.w;
    v = xr[2];
    a2.x += wih[8].x * v.x + wih[9].x * v.y + wih[10].x * v.z + wih[11].x * v.w;
    a2.y += wih[8].y * v.x + wih[9].y * v.y + wih[10].y * v.z + wih[11].y * v.w;
    v = xr[3];
    a3.x += wih[12].x * v.x + wih[13].x * v.y;
    a3.y += wih[12].y * v.x + wih[13].y * v.y;

#pragma unroll
    for (int k = 0; k < 64; k += 4) {
      fma2(a0, w2[k + 0], bcast(vLow, k + 0));
      fma2(a1, w2[k + 1], bcast(vLow, k + 1));
      fma2(a2, w2[k + 2], bcast(vLow, k + 2));
      fma2(a3, w2[k + 3], bcast(vLow, k + 3));
    }
#pragma unroll
    for (int k = 0; k < 64; k += 4) {
      fma2(a0, w2[64 + k + 0], bcast(vHigh, k + 0));
      fma2(a1, w2[64 + k + 1], bcast(vHigh, k + 1));
      fma2(a2, w2[64 + k + 2], bcast(vHigh, k + 2));
      fma2(a3, w2[64 + k + 3], bcast(vHigh, k + 3));
    }
    const float gA = biasA + ((a0.x + a1.x) + (a2.x + a3.x));  // i (j<128) / f
    const float gB = biasB + ((a0.y + a1.y) + (a2.y + a3.y));  // g (j<128) / o

    // balanced transcendentals in all threads, then exchange
    const float e0 = sigf(gA);                             // si or sf
    const float e1 = (j < H) ? tanhf(gB) : sigf(gB);       // tg or so
    if (j >= H) fgbuf[j - H] = make_float2(e0, e1);
    __syncthreads();

    if (j < H) {
      float2 fo = fgbuf[j];
      syn = fo.x * syn + e0 * e1;                // sf*syn + si*tanh(g)
      float reset = (mem - thr > 0.f) ? 1.f : 0.f;  // pre-update mem, detached
      mem = fo.y * tanhf(syn) - reset * thr;
      membuf[j] = mem;
      bool sp = (mem - thr) > 0.f;
      unsigned long long mask = __ballot(sp);
      if (lane == 0) spk[(size_t)(t * BATCH + b) * 2 + wav] = mask;
    }
    __syncthreads();
    vLow  = membuf[lane];
    vHigh = membuf[64 + lane];
  }
}

// ------------------------------------------- layer-2 input GEMM (chunked)
__global__ __launch_bounds__(256, 1) void g2_kernel(
    const unsigned long long* __restrict__ spk,  // [T,B,2]
    const float* __restrict__ Wih2,              // [512,128]
    const float* __restrict__ bih2,
    const float* __restrict__ bhh2,
    float* __restrict__ z2,                      // [ch,B,512]
    int t0, int rows_per_blk)
{
  const int j    = threadIdx.x;        // cols j and j+256
  const int lane = j & 63;
  float2 w2[128];
#pragma unroll
  for (int k = 0; k < 128; ++k) {
    w2[k].x = Wih2[j * 128 + k];
    w2[k].y = Wih2[(j + 256) * 128 + k];
  }
  const float biasA = bih2[j] + bhh2[j];
  const float biasB = bih2[j + 256] + bhh2[j + 256];

  const int r0   = blockIdx.x * rows_per_blk;
  const int rEnd = r0 + rows_per_blk;
  ulonglong2 nxt = *(const ulonglong2*)&spk[(size_t)(t0 * BATCH + r0) * 2];
  for (int r = r0; r < rEnd; ++r) {
    ulonglong2 cur = nxt;
    if (r + 1 < rEnd)
      nxt = *(const ulonglong2*)&spk[(size_t)(t0 * BATCH + r + 1) * 2];
    const float vLow  = ((cur.x >> lane) & 1ull) ? 1.f : 0.f;  // s[lane]
    const float vHigh = ((cur.y >> lane) & 1ull) ? 1.f : 0.f;  // s[64+lane]

    float2 a0 = {0.f, 0.f}, a1 = {0.f, 0.f}, a2 = {0.f, 0.f}, a3 = {0.f, 0.f};
#pragma unroll
    for (int k = 0; k < 64; k += 4) {
      fma2(a0, w2[k + 0], bcast(vLow, k + 0));
      fma2(a1, w2[k + 1], bcast(vLow, k + 1));
      fma2(a2, w2[k + 2], bcast(vLow, k + 2));
      fma2(a3, w2[k + 3], bcast(vLow, k + 3));
    }
#pragma unroll
    for (int k = 0; k < 64; k += 4) {
      fma2(a0, w2[64 + k + 0], bcast(vHigh, k + 0));
      fma2(a1, w2[64 + k + 1], bcast(vHigh, k + 1));
      fma2(a2, w2[64 + k + 2], bcast(vHigh, k + 2));
      fma2(a3, w2[64 + k + 3], bcast(vHigh, k + 3));
    }
    z2[(size_t)r * G4 + j]       = biasA + ((a0.x + a1.x) + (a2.x + a3.x));
    z2[(size_t)r * G4 + j + 256] = biasB + ((a0.y + a1.y) + (a2.y + a3.y));
  }
}

// ---------------------------------------------------------------- layer 2
__global__ __launch_bounds__(256, 1) void r2_kernel(
    const float* __restrict__ z2,     // [ch,B,512]
    const float* __restrict__ Whh2,   // [512,128]
    const float* __restrict__ thr2p,
    float* __restrict__ state,        // [3][B][H] : syn2, mem2, sum(mem2)
    int ch, int first)
{
  const int b    = blockIdx.x;
  const int j    = threadIdx.x;        // rows j and j+256
  float2 w2[128];
#pragma unroll
  for (int k = 0; k < 128; ++k) {
    w2[k].x = Whh2[j * 128 + k];
    w2[k].y = Whh2[(j + 256) * 128 + k];
  }
  const float thr = thr2p[0];
  __shared__ float membuf[H];
  __shared__ float2 fgbuf[H];

  float syn = 0.f, mem = 0.f, sum = 0.f;
  if (j < H) {
    if (!first) {
      syn = state[b * H + j];
      mem = state[BATCH * H + b * H + j];
      sum = state[2 * BATCH * H + b * H + j];
    }
    membuf[j] = mem;
  }
  __syncthreads();
  const int lane = j & 63;
  float vLow  = membuf[lane];
  float vHigh = membuf[64 + lane];

  float zA = z2[(size_t)b * G4 + j];
  float zB = z2[(size_t)b * G4 + j + 256];
  for (int tl = 0; tl < ch; ++tl) {
    float zcA = zA, zcB = zB;
    if (tl + 1 < ch) {
      zA = z2[(size_t)((tl + 1) * BATCH + b) * G4 + j];
      zB = z2[(size_t)((tl + 1) * BATCH + b) * G4 + j + 256];
    }
    float2 a0 = {0.f, 0.f}, a1 = {0.f, 0.f}, a2 = {0.f, 0.f}, a3 = {0.f, 0.f};
#pragma unroll
    for (int k = 0; k < 64; k += 4) {
      fma2(a0, w2[k + 0], bcast(vLow, k + 0));
      fma2(a1, w2[k + 1], bcast(vLow, k + 1));
      fma2(a2, w2[k + 2], bcast(vLow, k + 2));
      fma2(a3, w2[k + 3], bcast(vLow, k + 3));
    }
#pragma unroll
    for (int k = 0; k < 64; k += 4) {
      fma2(a0, w2[64 + k + 0], bcast(vHigh, k + 0));
      fma2(a1, w2[64 + k + 1], bcast(vHigh, k + 1));
      fma2(a2, w2[64 + k + 2], bcast(vHigh, k + 2));
      fma2(a3, w2[64 + k + 3], bcast(vHigh, k + 3));
    }
    const float gA = zcA + ((a0.x + a1.x) + (a2.x + a3.x));  // i / f
    const float gB = zcB + ((a0.y + a1.y) + (a2.y + a3.y));  // g / o

    const float e0 = sigf(gA);
    const float e1 = (j < H) ? tanhf(gB) : sigf(gB);
    if (j >= H) fgbuf[j - H] = make_float2(e0, e1);
    __syncthreads();

    if (j < H) {
      float2 fo = fgbuf[j];
      syn = fo.x * syn + e0 * e1;
      float reset = (mem - thr > 0.f) ? 1.f : 0.f;
      mem = fo.y * tanhf(syn) - reset * thr;
      sum += mem;
      membuf[j] = mem;
    }
    __syncthreads();
    vLow  = membuf[lane];
    vHigh = membuf[64 + lane];
  }
  if (j < H) {
    state[b * H + j] = syn;
    state[BATCH * H + b * H + j] = mem;
    state[2 * BATCH * H + b * H + j] = sum;
  }
}

// ---------------------------------------------------------------- readout
__global__ void fc_kernel(const float* __restrict__ sumbuf,  // [B,H] sum over t
                          const float* __restrict__ fcw,     // [NC,H]
                          const float* __restrict__ fcb,     // [NC]
                          float* __restrict__ out)           // [B,NC]
{
  int g = blockIdx.x * blockDim.x + threadIdx.x;
  if (g >= BATCH * NC) return;
  int b = g / NC, c = g % NC;
  const float* s  = sumbuf + b * H;
  const float* wr = fcw + c * H;
  float acc = 0.f;
#pragma unroll
  for (int hh = 0; hh < H; hh += 4) {
    float4 sv = *(const float4*)(s + hh);
    float4 wv = *(const float4*)(wr + hh);
    acc += sv.x * wv.x + sv.y * wv.y + sv.z * wv.z + sv.w * wv.w;
  }
  out[g] = fcb[c] + acc * (1.f / 1024.f);
}

extern "C" void kernel_launch(void* const* d_in, const int* in_sizes, int n_in,
                              void* d_out, int out_size, void* d_ws, size_t ws_size,
                              hipStream_t stream)
{
  (void)in_sizes; (void)n_in; (void)out_size;
  const float* x    = (const float*)d_in[0];
  const float* Wih1 = (const float*)d_in[1];
  const float* Whh1 = (const float*)d_in[2];
  const float* bih1 = (const float*)d_in[3];
  const float* bhh1 = (const float*)d_in[4];
  const float* thr1 = (const float*)d_in[5];
  const float* Wih2 = (const float*)d_in[6];
  const float* Whh2 = (const float*)d_in[7];
  const float* bih2 = (const float*)d_in[8];
  const float* bhh2 = (const float*)d_in[9];
  const float* thr2 = (const float*)d_in[10];
  const float* fcw  = (const float*)d_in[11];
  const float* fcb  = (const float*)d_in[12];

  char* ws = (char*)d_ws;
  unsigned long long* spk = (unsigned long long*)ws;            // 4 MB
  float* state = (float*)(ws + (4u << 20));                     // 384 KB used
  float* z2    = (float*)(ws + (4u << 20) + (1u << 19));

  // pick largest power-of-two time-chunk whose Z2 buffer fits the workspace
  size_t hdr = (4u << 20) + (1u << 19);
  size_t avail = (ws_size > hdr) ? (ws_size - hdr) : 0;
  int ch = 1024;
  while (ch > 8 && (size_t)ch * BATCH * G4 * sizeof(float) > avail) ch >>= 1;

  r1_kernel<<<256, 256, 0, stream>>>(x, Wih1, Whh1, bih1, bhh1, thr1, spk);

  int first = 1;
  for (int t0 = 0; t0 < T_STEPS; t0 += ch) {
    // 2048 blocks; rows_per_blk = ch*BATCH/2048 = ch/8  (ch >= 8)
    g2_kernel<<<2048, 256, 0, stream>>>(spk, Wih2, bih2, bhh2, z2, t0, ch / 8);
    r2_kernel<<<256, 256, 0, stream>>>(z2, Whh2, thr2, state, ch, first);
    first = 0;
  }

  fc_kernel<<<(BATCH * NC + 255) / 256, 256, 0, stream>>>(
      state + 2 * BATCH * H, fcw, fcb, (float*)d_out);
}